// Round 3
// baseline (1309.597 us; speedup 1.0000x reference)
//
#include <hip/hip_runtime.h>
#include <stdint.h>

typedef unsigned short u16;
typedef __attribute__((ext_vector_type(8))) short bf16x8;
typedef __attribute__((ext_vector_type(4))) float f32x4;

#define SEQ    2048
#define NB     2
#define NHEAD  16
#define DHEAD  128
#define DMODEL 2048
#define DFFN   8192
#define MROWS  4096   // NB*SEQ

__device__ __forceinline__ u16 f2bf(float x) {
  union { float f; uint32_t u; } v; v.f = x;
  return (u16)((v.u + 0x7fffu + ((v.u >> 16) & 1u)) >> 16);
}
__device__ __forceinline__ float bf2f(u16 h) {
  union { uint32_t u; float f; } v; v.u = ((uint32_t)h) << 16;
  return v.f;
}
__device__ __forceinline__ void gload16(const void* g, void* l) {
  __builtin_amdgcn_global_load_lds((const __attribute__((address_space(1))) void*)g,
                                   (__attribute__((address_space(3))) void*)l,
                                   16, 0, 0);
}
__device__ __forceinline__ float blockSum256(float v) {
  __shared__ float red[4];
  #pragma unroll
  for (int m = 1; m < 64; m <<= 1) v += __shfl_xor(v, m, 64);
  int w = threadIdx.x >> 6;
  if ((threadIdx.x & 63) == 0) red[w] = v;
  __syncthreads();
  float s = red[0] + red[1] + red[2] + red[3];
  __syncthreads();
  return s;
}

// ---------------- weight transpose fp32 (R,C) -> bf16 (C,R) ----------------
__global__ void transpose_w(const float* __restrict__ in, u16* __restrict__ out, int R, int C) {
  __shared__ float tile[32][33];
  int c0 = blockIdx.x * 32, r0 = blockIdx.y * 32;
  int tx = threadIdx.x, ty = threadIdx.y;
  #pragma unroll
  for (int i = 0; i < 4; ++i)
    tile[ty + 8*i][tx] = in[(size_t)(r0 + ty + 8*i) * C + c0 + tx];
  __syncthreads();
  #pragma unroll
  for (int i = 0; i < 4; ++i)
    out[(size_t)(c0 + ty + 8*i) * R + r0 + tx] = f2bf(tile[tx][ty + 8*i]);
}

// ---- ln_first: x(B,S,2049) -> v1 = log_map(x) fp32, t1 = scale*v1/rms bf16 ----
__global__ void ln_first(const float* __restrict__ x, const float* __restrict__ scale,
                         float* __restrict__ v1, u16* __restrict__ t1) {
  int row = blockIdx.x;
  const float* xr = x + (size_t)row * (DMODEL + 1) + 1;
  float vals[8]; float ss = 0.f;
  #pragma unroll
  for (int i = 0; i < 8; ++i) {
    int idx = threadIdx.x + 256 * i;
    vals[i] = xr[idx];
    ss += vals[i] * vals[i];
  }
  ss = blockSum256(ss);
  float n = sqrtf(ss);
  float f = (n < 1e-6f) ? (1.0f - n * n * (1.0f/6.0f)) : (asinhf(n) / n);
  float rms = sqrtf(f * f * ss * (1.0f / DMODEL) + 1e-6f);
  float ir = 1.0f / rms;
  #pragma unroll
  for (int i = 0; i < 8; ++i) {
    int idx = threadIdx.x + 256 * i;
    float v = f * vals[i];
    v1[(size_t)row * DMODEL + idx] = v;
    t1[(size_t)row * DMODEL + idx] = f2bf(scale[idx] * v * ir);
  }
}

// ---- rms_mid: t = scale*u/rms(u) ----
__global__ void rms_mid(const float* __restrict__ u, const float* __restrict__ scale,
                        u16* __restrict__ t) {
  int row = blockIdx.x;
  const float* ur = u + (size_t)row * DMODEL;
  float vals[8]; float ss = 0.f;
  #pragma unroll
  for (int i = 0; i < 8; ++i) { int idx = threadIdx.x + 256*i; vals[i] = ur[idx]; ss += vals[i]*vals[i]; }
  ss = blockSum256(ss);
  float ir = 1.0f / sqrtf(ss * (1.0f / DMODEL) + 1e-6f);
  #pragma unroll
  for (int i = 0; i < 8; ++i) {
    int idx = threadIdx.x + 256*i;
    t[(size_t)row*DMODEL + idx] = f2bf(scale[idx]*vals[i]*ir);
  }
}

// ---- final: out = exp_map_stable(u), row length 2049 ----
__global__ void final_exp(const float* __restrict__ u, float* __restrict__ out) {
  int row = blockIdx.x;
  const float* ur = u + (size_t)row * DMODEL;
  float vals[8]; float ss = 0.f;
  #pragma unroll
  for (int i = 0; i < 8; ++i) { int idx = threadIdx.x + 256*i; vals[i] = ur[idx]; ss += vals[i]*vals[i]; }
  ss = blockSum256(ss);
  float n = sqrtf(ss);
  float f = (n < 1e-6f) ? (1.0f + n*n*(1.0f/6.0f)) : (sinhf(n)/n);
  float* orow = out + (size_t)row * (DMODEL + 1);
  if (threadIdx.x == 0) orow[0] = sqrtf(1.0f + f*f*ss);
  #pragma unroll
  for (int i = 0; i < 8; ++i) { int idx = threadIdx.x + 256*i; orow[1+idx] = f*vals[i]; }
}

// ---------------- GEMM: C(M,N) = A(M,K)bf16 @ Bt(N,K)bf16^T ----------------
// EPI 0: store bf16; EPI 1: Cf = acc + add (fp32); EPI 2: gelu(acc) -> bf16
template<int EPI>
__global__ __launch_bounds__(256, 3) void gemm_bt(
    const u16* __restrict__ A, const u16* __restrict__ Bt,
    u16* __restrict__ Cb, float* Cf, const float* add,
    int M, int N, int K)
{
  __shared__ u16 As[128 * 32];
  __shared__ u16 Bs[128 * 32];
  const int tid = threadIdx.x;
  const int w = tid >> 6, lane = tid & 63;
  const int lrow = lane & 15, kq = lane >> 4;
  const int m0 = blockIdx.y * 128, n0 = blockIdx.x * 128;
  const int wm = w >> 1, wn = w & 1;
  f32x4 acc[4][4] = {};
  for (int k0 = 0; k0 < K; k0 += 32) {
    __syncthreads();
    #pragma unroll
    for (int j = 0; j < 2; ++j) {
      int ebase = j * 2048 + w * 512;      // wave-uniform element base in tile
      int e = ebase + lane * 8;
      int row = e >> 5, col = e & 31;
      gload16(A  + (size_t)(m0 + row) * K + k0 + col, &As[ebase]);
      gload16(Bt + (size_t)(n0 + row) * K + k0 + col, &Bs[ebase]);
    }
    __syncthreads();
    bf16x8 av[4], bv[4];
    #pragma unroll
    for (int i = 0; i < 4; ++i) av[i] = *(const bf16x8*)&As[(wm*64 + i*16 + lrow)*32 + kq*8];
    #pragma unroll
    for (int j = 0; j < 4; ++j) bv[j] = *(const bf16x8*)&Bs[(wn*64 + j*16 + lrow)*32 + kq*8];
    #pragma unroll
    for (int i = 0; i < 4; ++i)
      #pragma unroll
      for (int j = 0; j < 4; ++j)
        acc[i][j] = __builtin_amdgcn_mfma_f32_16x16x32_bf16(av[i], bv[j], acc[i][j], 0, 0, 0);
  }
  #pragma unroll
  for (int i = 0; i < 4; ++i)
    #pragma unroll
    for (int j = 0; j < 4; ++j)
      #pragma unroll
      for (int r = 0; r < 4; ++r) {
        int row = m0 + wm*64 + i*16 + kq*4 + r;
        int col = n0 + wn*64 + j*16 + lrow;
        size_t idx = (size_t)row * N + col;
        float v = acc[i][j][r];
        if (EPI == 0) {
          Cb[idx] = f2bf(v);
        } else if (EPI == 1) {
          Cf[idx] = v + add[idx];
        } else {
          float g = 0.5f * v * (1.0f + erff(v * 0.70710678118654752f));
          Cb[idx] = f2bf(g);
        }
      }
}

// ---- prep: split heads + per-head exp_map. in (B*S, instride) bf16 at col off ->
//      Lout[(b*H+h)*S + s][d] = sinc*v (bf16), l0 = x0 component (fp32) ----
__global__ void prep_qk(const u16* __restrict__ in, const float* __restrict__ headK,
                        u16* __restrict__ Lout, float* __restrict__ l0,
                        int instride, int off) {
  int gid = blockIdx.x * 4 + (threadIdx.x >> 6);
  int lane = threadIdx.x & 63;
  int b = gid >> 15;            // /(H*S)=32768
  int rem = gid & 32767;
  int h = rem >> 11;            // /S=2048
  int s = rem & 2047;
  const u16* src = in + ((size_t)(b * SEQ + s)) * instride + off + h * DHEAD + lane * 2;
  float v0 = bf2f(src[0]), v1 = bf2f(src[1]);
  float nn = v0*v0 + v1*v1;
  #pragma unroll
  for (int m = 1; m < 64; m <<= 1) nn += __shfl_xor(nn, m, 64);
  float Kh = headK[h];
  float sk = sqrtf(-Kh);
  float a = sk * sqrtf(nn);
  float f = (a < 1e-6f) ? (1.0f + a*a*(1.0f/6.0f)) : (sinhf(a) / a);
  u16* dst = Lout + (size_t)gid * DHEAD + lane * 2;
  dst[0] = f2bf(f * v0);
  dst[1] = f2bf(f * v1);
  if (lane == 0) l0[gid] = sqrtf(-1.0f/Kh + f*f*nn);
}

// ---- vtrans: in (B*S, instride) bf16 at col off -> VT[(b*H+h)*DH + d][s] ----
__global__ void vtrans(const u16* __restrict__ vb, u16* __restrict__ VT,
                       int instride, int off) {
  __shared__ u16 tile[32][33];
  int bh = blockIdx.x;
  int b = bh >> 4, h = bh & 15;
  int s0 = blockIdx.y * 32, d0 = blockIdx.z * 32;
  int tx = threadIdx.x, ty = threadIdx.y;
  #pragma unroll
  for (int i = 0; i < 4; ++i)
    tile[ty + 8*i][tx] = vb[((size_t)(b*SEQ + s0 + ty + 8*i)) * instride + off + h*DHEAD + d0 + tx];
  __syncthreads();
  #pragma unroll
  for (int i = 0; i < 4; ++i)
    VT[((size_t)bh*DHEAD + d0 + ty + 8*i) * SEQ + s0 + tx] = tile[tx][ty + 8*i];
}

// ---------------- flash attention v3: barrier-free, fixed max (scores<=0) ----------------
// block = 4 independent waves, each owns 32 q-rows; K/V B-frags read from global (L2);
// P transposed C->A layout through per-wave LDS.
__global__ __launch_bounds__(256, 3) void attn_kernel(
    const u16* __restrict__ Ql, const u16* __restrict__ Kl,
    const u16* __restrict__ VT, const float* __restrict__ ql0,
    const float* __restrict__ kl0, const float* __restrict__ headK,
    u16* __restrict__ out) {
  __shared__ u16 plds[4][32 * 40];   // per-wave P buffer [qlocal][klocal], stride 40
  const int tid = threadIdx.x, w = tid >> 6, lane = tid & 63;
  const int lrow = lane & 15, kq = lane >> 4;
  const int q0 = (int)(gridDim.x - 1 - blockIdx.x) * 128 + w * 32;  // long blocks first
  const int bh = blockIdx.y;
  const int b = bh >> 4, h = bh & 15;
  const float Kh = headK[h];
  const float LOG2E = 1.44269504088896f;
  const float isd = 0.088388347648318447f;   // 1/sqrt(128)
  const float sc_mul = 2.0f * isd * LOG2E;
  const float sc_add = (-2.0f / Kh) * isd * LOG2E;

  // preload Q fragments (2 m-tiles x 4 d-chunks) and q0 components
  bf16x8 aq[2][4];
  const u16* qbase = Ql + ((size_t)bh * SEQ + q0) * DHEAD;
  #pragma unroll
  for (int m = 0; m < 2; ++m)
    #pragma unroll
    for (int dc = 0; dc < 4; ++dc)
      aq[m][dc] = *(const bf16x8*)&qbase[(size_t)(m*16 + lrow) * DHEAD + dc*32 + kq*8];
  float q0r[2][4];
  #pragma unroll
  for (int m = 0; m < 2; ++m)
    #pragma unroll
    for (int r = 0; r < 4; ++r)
      q0r[m][r] = ql0[(size_t)bh * SEQ + q0 + m*16 + kq*4 + r];

  const u16* kbase  = Kl + (size_t)bh * SEQ * DHEAD;
  const u16* vtbase = VT + (size_t)bh * DHEAD * SEQ;
  const float* kl0b = kl0 + (size_t)bh * SEQ;
  u16* pw = &plds[w][0];

  float lacc[2][4] = {};
  f32x4 o[2][8] = {};

  for (int k0 = 0; k0 <= q0; k0 += 32) {
    const bool diag = (k0 == q0);
    // ---- QK^T: 16 q x 32 k per m-tile ----
    f32x4 sc[2][2] = {};
    #pragma unroll
    for (int dc = 0; dc < 4; ++dc) {
      bf16x8 bk0 = *(const bf16x8*)&kbase[(size_t)(k0 + lrow) * DHEAD + dc*32 + kq*8];
      bf16x8 bk1 = *(const bf16x8*)&kbase[(size_t)(k0 + 16 + lrow) * DHEAD + dc*32 + kq*8];
      #pragma unroll
      for (int m = 0; m < 2; ++m) {
        sc[m][0] = __builtin_amdgcn_mfma_f32_16x16x32_bf16(aq[m][dc], bk0, sc[m][0], 0, 0, 0);
        sc[m][1] = __builtin_amdgcn_mfma_f32_16x16x32_bf16(aq[m][dc], bk1, sc[m][1], 0, 0, 0);
      }
    }
    float kc0 = kl0b[k0 + lrow], kc1 = kl0b[k0 + 16 + lrow];
    // ---- softmax numerator (max fixed at 0: Lorentz scores <= 0) ----
    #pragma unroll
    for (int m = 0; m < 2; ++m)
      #pragma unroll
      for (int r = 0; r < 4; ++r) {
        float p0 = exp2f((sc[m][0][r] - q0r[m][r] * kc0) * sc_mul + sc_add);
        float p1 = exp2f((sc[m][1][r] - q0r[m][r] * kc1) * sc_mul + sc_add);
        if (diag) {
          int qloc = m*16 + kq*4 + r;
          p0 = (lrow <= qloc) ? p0 : 0.f;
          p1 = (16 + lrow <= qloc) ? p1 : 0.f;
        }
        lacc[m][r] += p0 + p1;
        pw[(m*16 + kq*4 + r) * 40 + lrow]      = f2bf(p0);
        pw[(m*16 + kq*4 + r) * 40 + 16 + lrow] = f2bf(p1);
      }
    __asm__ __volatile__("s_waitcnt lgkmcnt(0)" ::: "memory");
    // ---- P @ V ----
    bf16x8 ap0 = *(const bf16x8*)&pw[(size_t)lrow * 40 + kq*8];
    bf16x8 ap1 = *(const bf16x8*)&pw[(size_t)(16 + lrow) * 40 + kq*8];
    #pragma unroll
    for (int n = 0; n < 8; ++n) {
      bf16x8 bv = *(const bf16x8*)&vtbase[(size_t)(n*16 + lrow) * SEQ + k0 + kq*8];
      o[0][n] = __builtin_amdgcn_mfma_f32_16x16x32_bf16(ap0, bv, o[0][n], 0, 0, 0);
      o[1][n] = __builtin_amdgcn_mfma_f32_16x16x32_bf16(ap1, bv, o[1][n], 0, 0, 0);
    }
  }
  // ---- finalize: row sums (reduce over lrow within each 16-lane group) ----
  float rcl[2][4];
  #pragma unroll
  for (int m = 0; m < 2; ++m)
    #pragma unroll
    for (int r = 0; r < 4; ++r) {
      float s = lacc[m][r];
      #pragma unroll
      for (int mm = 1; mm < 16; mm <<= 1) s += __shfl_xor(s, mm, 16);
      rcl[m][r] = 1.0f / s;
    }
  #pragma unroll
  for (int m = 0; m < 2; ++m)
    #pragma unroll
    for (int n = 0; n < 8; ++n)
      #pragma unroll
      for (int r = 0; r < 4; ++r) {
        int qg = q0 + m*16 + kq*4 + r;
        out[((size_t)b * SEQ + qg) * DMODEL + h * DHEAD + n*16 + lrow] =
            f2bf(o[m][n][r] * rcl[m][r]);
      }
}

extern "C" void kernel_launch(void* const* d_in, const int* in_sizes, int n_in,
                              void* d_out, int out_size, void* d_ws, size_t ws_size,
                              hipStream_t stream) {
  const float* x      = (const float*)d_in[0];
  // d_in[1] = mask (causal tril; applied analytically)
  const float* scale1 = (const float*)d_in[2];
  const float* scale2 = (const float*)d_in[3];
  const float* Wq     = (const float*)d_in[4];
  const float* Wk     = (const float*)d_in[5];
  const float* Wv     = (const float*)d_in[6];
  const float* Wo     = (const float*)d_in[7];
  const float* headK  = (const float*)d_in[8];
  const float* W1     = (const float*)d_in[9];
  const float* W2     = (const float*)d_in[10];
  float* out = (float*)d_out;

  char* p = (char*)d_ws;
  size_t off = 0;
  auto take = [&](size_t bytes) -> char* {
    char* r = p + off;
    off += (bytes + 255) & ~(size_t)255;
    return r;
  };
  u16* WqT = (u16*)take((size_t)DMODEL*DMODEL*2);   // WqT/WkT/WvT contiguous => (6144,2048)
  u16* WkT = (u16*)take((size_t)DMODEL*DMODEL*2);
  u16* WvT = (u16*)take((size_t)DMODEL*DMODEL*2);
  u16* WoT = (u16*)take((size_t)DMODEL*DMODEL*2);
  u16* W1T = (u16*)take((size_t)DMODEL*DFFN*2);
  u16* W2T = (u16*)take((size_t)DMODEL*DFFN*2);
  float* vres = (float*)take((size_t)MROWS*DMODEL*4);   // v1 -> u2 -> u3 (in place)
  u16* tbuf = (u16*)take((size_t)MROWS*DMODEL*2);       // t1, attn_out, t2
  u16* qkvb = (u16*)take((size_t)MROWS*3*DMODEL*2);     // fused QKV out (4096 x 6144)
  u16* Qlb  = (u16*)take((size_t)MROWS*DMODEL*2);       // qkvb+Qlb = 64MB => FFN hidden
  u16* Klb  = (u16*)take((size_t)MROWS*DMODEL*2);
  u16* VTb  = (u16*)take((size_t)MROWS*DMODEL*2);
  float* q0b = (float*)take((size_t)NB*NHEAD*SEQ*4);
  float* k0b = (float*)take((size_t)NB*NHEAD*SEQ*4);
  u16* hbuf = qkvb;     // reuse qkvb..Qlb contiguous 64MB = MROWS*DFFN bf16
  u16* attnout = tbuf;  // t1 consumed by QKV gemm before attention writes here

  dim3 tb(32, 8);
  transpose_w<<<dim3(DMODEL/32, DMODEL/32), tb, 0, stream>>>(Wq, WqT, DMODEL, DMODEL);
  transpose_w<<<dim3(DMODEL/32, DMODEL/32), tb, 0, stream>>>(Wk, WkT, DMODEL, DMODEL);
  transpose_w<<<dim3(DMODEL/32, DMODEL/32), tb, 0, stream>>>(Wv, WvT, DMODEL, DMODEL);
  transpose_w<<<dim3(DMODEL/32, DMODEL/32), tb, 0, stream>>>(Wo, WoT, DMODEL, DMODEL);
  transpose_w<<<dim3(DFFN/32,   DMODEL/32), tb, 0, stream>>>(W1, W1T, DMODEL, DFFN);
  transpose_w<<<dim3(DMODEL/32, DFFN/32),   tb, 0, stream>>>(W2, W2T, DFFN, DMODEL);

  ln_first<<<MROWS, 256, 0, stream>>>(x, scale1, vres, tbuf);

  // fused QKV: N = 6144
  gemm_bt<0><<<dim3(3*DMODEL/128, MROWS/128), 256, 0, stream>>>(tbuf, WqT, qkvb, nullptr, nullptr, MROWS, 3*DMODEL, DMODEL);

  prep_qk<<<NB*NHEAD*SEQ/4, 256, 0, stream>>>(qkvb, headK, Qlb, q0b, 3*DMODEL, 0);
  prep_qk<<<NB*NHEAD*SEQ/4, 256, 0, stream>>>(qkvb, headK, Klb, k0b, 3*DMODEL, DMODEL);
  vtrans<<<dim3(NB*NHEAD, SEQ/32, DHEAD/32), tb, 0, stream>>>(qkvb, VTb, 3*DMODEL, 2*DMODEL);

  attn_kernel<<<dim3(SEQ/128, NB*NHEAD), 256, 0, stream>>>(Qlb, Klb, VTb, q0b, k0b, headK, attnout);

  gemm_bt<1><<<dim3(DMODEL/128, MROWS/128), 256, 0, stream>>>(attnout, WoT, nullptr, vres, vres, MROWS, DMODEL, DMODEL);

  rms_mid<<<MROWS, 256, 0, stream>>>(vres, scale2, tbuf);

  gemm_bt<2><<<dim3(DFFN/128, MROWS/128), 256, 0, stream>>>(tbuf, W1T, hbuf, nullptr, nullptr, MROWS, DFFN, DMODEL);

  gemm_bt<1><<<dim3(DMODEL/128, MROWS/128), 256, 0, stream>>>(hbuf, W2T, nullptr, vres, vres, MROWS, DMODEL, DFFN);

  final_exp<<<MROWS, 256, 0, stream>>>(vres, out);

  (void)in_sizes; (void)n_in; (void)out_size; (void)ws_size;
}

// Round 4
// 1045.744 us; speedup vs baseline: 1.2523x; 1.2523x over previous
//
#include <hip/hip_runtime.h>
#include <stdint.h>

typedef unsigned short u16;
typedef __attribute__((ext_vector_type(8))) short bf16x8;
typedef __attribute__((ext_vector_type(4))) float f32x4;

#define SEQ    2048
#define NB     2
#define NHEAD  16
#define DHEAD  128
#define DMODEL 2048
#define DFFN   8192
#define MROWS  4096   // NB*SEQ

__device__ __forceinline__ u16 f2bf(float x) {
  union { float f; uint32_t u; } v; v.f = x;
  return (u16)((v.u + 0x7fffu + ((v.u >> 16) & 1u)) >> 16);
}
__device__ __forceinline__ float bf2f(u16 h) {
  union { uint32_t u; float f; } v; v.u = ((uint32_t)h) << 16;
  return v.f;
}
__device__ __forceinline__ void gload16(const void* g, void* l) {
  __builtin_amdgcn_global_load_lds((const __attribute__((address_space(1))) void*)g,
                                   (__attribute__((address_space(3))) void*)l,
                                   16, 0, 0);
}
__device__ __forceinline__ float blockSum256(float v) {
  __shared__ float red[4];
  #pragma unroll
  for (int m = 1; m < 64; m <<= 1) v += __shfl_xor(v, m, 64);
  int w = threadIdx.x >> 6;
  if ((threadIdx.x & 63) == 0) red[w] = v;
  __syncthreads();
  float s = red[0] + red[1] + red[2] + red[3];
  __syncthreads();
  return s;
}

// ---------------- weight transpose fp32 (R,C) -> bf16 (C,R) ----------------
__global__ void transpose_w(const float* __restrict__ in, u16* __restrict__ out, int R, int C) {
  __shared__ float tile[32][33];
  int c0 = blockIdx.x * 32, r0 = blockIdx.y * 32;
  int tx = threadIdx.x, ty = threadIdx.y;
  #pragma unroll
  for (int i = 0; i < 4; ++i)
    tile[ty + 8*i][tx] = in[(size_t)(r0 + ty + 8*i) * C + c0 + tx];
  __syncthreads();
  #pragma unroll
  for (int i = 0; i < 4; ++i)
    out[(size_t)(c0 + ty + 8*i) * R + r0 + tx] = f2bf(tile[tx][ty + 8*i]);
}

// ---- ln_first: x(B,S,2049) -> v1 = log_map(x) fp32, t1 = scale*v1/rms bf16 ----
__global__ void ln_first(const float* __restrict__ x, const float* __restrict__ scale,
                         float* __restrict__ v1, u16* __restrict__ t1) {
  int row = blockIdx.x;
  const float* xr = x + (size_t)row * (DMODEL + 1) + 1;
  float vals[8]; float ss = 0.f;
  #pragma unroll
  for (int i = 0; i < 8; ++i) {
    int idx = threadIdx.x + 256 * i;
    vals[i] = xr[idx];
    ss += vals[i] * vals[i];
  }
  ss = blockSum256(ss);
  float n = sqrtf(ss);
  float f = (n < 1e-6f) ? (1.0f - n * n * (1.0f/6.0f)) : (asinhf(n) / n);
  float rms = sqrtf(f * f * ss * (1.0f / DMODEL) + 1e-6f);
  float ir = 1.0f / rms;
  #pragma unroll
  for (int i = 0; i < 8; ++i) {
    int idx = threadIdx.x + 256 * i;
    float v = f * vals[i];
    v1[(size_t)row * DMODEL + idx] = v;
    t1[(size_t)row * DMODEL + idx] = f2bf(scale[idx] * v * ir);
  }
}

// ---- rms_mid: t = scale*u/rms(u) ----
__global__ void rms_mid(const float* __restrict__ u, const float* __restrict__ scale,
                        u16* __restrict__ t) {
  int row = blockIdx.x;
  const float* ur = u + (size_t)row * DMODEL;
  float vals[8]; float ss = 0.f;
  #pragma unroll
  for (int i = 0; i < 8; ++i) { int idx = threadIdx.x + 256*i; vals[i] = ur[idx]; ss += vals[i]*vals[i]; }
  ss = blockSum256(ss);
  float ir = 1.0f / sqrtf(ss * (1.0f / DMODEL) + 1e-6f);
  #pragma unroll
  for (int i = 0; i < 8; ++i) {
    int idx = threadIdx.x + 256*i;
    t[(size_t)row*DMODEL + idx] = f2bf(scale[idx]*vals[i]*ir);
  }
}

// ---- final: out = exp_map_stable(u), row length 2049 ----
__global__ void final_exp(const float* __restrict__ u, float* __restrict__ out) {
  int row = blockIdx.x;
  const float* ur = u + (size_t)row * DMODEL;
  float vals[8]; float ss = 0.f;
  #pragma unroll
  for (int i = 0; i < 8; ++i) { int idx = threadIdx.x + 256*i; vals[i] = ur[idx]; ss += vals[i]*vals[i]; }
  ss = blockSum256(ss);
  float n = sqrtf(ss);
  float f = (n < 1e-6f) ? (1.0f + n*n*(1.0f/6.0f)) : (sinhf(n)/n);
  float* orow = out + (size_t)row * (DMODEL + 1);
  if (threadIdx.x == 0) orow[0] = sqrtf(1.0f + f*f*ss);
  #pragma unroll
  for (int i = 0; i < 8; ++i) { int idx = threadIdx.x + 256*i; orow[1+idx] = f*vals[i]; }
}

// ---------------- GEMM: C(M,N) = A(M,K)bf16 @ Bt(N,K)bf16^T ----------------
// EPI 0: store bf16; EPI 1: Cf = acc + add (fp32); EPI 2: gelu(acc) -> bf16
template<int EPI>
__global__ __launch_bounds__(256, 3) void gemm_bt(
    const u16* __restrict__ A, const u16* __restrict__ Bt,
    u16* __restrict__ Cb, float* Cf, const float* add,
    int M, int N, int K)
{
  __shared__ u16 As[128 * 32];
  __shared__ u16 Bs[128 * 32];
  const int tid = threadIdx.x;
  const int w = tid >> 6, lane = tid & 63;
  const int lrow = lane & 15, kq = lane >> 4;
  const int m0 = blockIdx.y * 128, n0 = blockIdx.x * 128;
  const int wm = w >> 1, wn = w & 1;
  f32x4 acc[4][4] = {};
  for (int k0 = 0; k0 < K; k0 += 32) {
    __syncthreads();
    #pragma unroll
    for (int j = 0; j < 2; ++j) {
      int ebase = j * 2048 + w * 512;      // wave-uniform element base in tile
      int e = ebase + lane * 8;
      int row = e >> 5, col = e & 31;
      gload16(A  + (size_t)(m0 + row) * K + k0 + col, &As[ebase]);
      gload16(Bt + (size_t)(n0 + row) * K + k0 + col, &Bs[ebase]);
    }
    __syncthreads();
    bf16x8 av[4], bv[4];
    #pragma unroll
    for (int i = 0; i < 4; ++i) av[i] = *(const bf16x8*)&As[(wm*64 + i*16 + lrow)*32 + kq*8];
    #pragma unroll
    for (int j = 0; j < 4; ++j) bv[j] = *(const bf16x8*)&Bs[(wn*64 + j*16 + lrow)*32 + kq*8];
    #pragma unroll
    for (int i = 0; i < 4; ++i)
      #pragma unroll
      for (int j = 0; j < 4; ++j)
        acc[i][j] = __builtin_amdgcn_mfma_f32_16x16x32_bf16(av[i], bv[j], acc[i][j], 0, 0, 0);
  }
  #pragma unroll
  for (int i = 0; i < 4; ++i)
    #pragma unroll
    for (int j = 0; j < 4; ++j)
      #pragma unroll
      for (int r = 0; r < 4; ++r) {
        int row = m0 + wm*64 + i*16 + kq*4 + r;
        int col = n0 + wn*64 + j*16 + lrow;
        size_t idx = (size_t)row * N + col;
        float v = acc[i][j][r];
        if (EPI == 0) {
          Cb[idx] = f2bf(v);
        } else if (EPI == 1) {
          Cf[idx] = v + add[idx];
        } else {
          float g = 0.5f * v * (1.0f + erff(v * 0.70710678118654752f));
          Cb[idx] = f2bf(g);
        }
      }
}

// ---- prep: split heads + per-head exp_map ----
__global__ void prep_qk(const u16* __restrict__ in, const float* __restrict__ headK,
                        u16* __restrict__ Lout, float* __restrict__ l0,
                        int instride, int off) {
  int gid = blockIdx.x * 4 + (threadIdx.x >> 6);
  int lane = threadIdx.x & 63;
  int b = gid >> 15;
  int rem = gid & 32767;
  int h = rem >> 11;
  int s = rem & 2047;
  const u16* src = in + ((size_t)(b * SEQ + s)) * instride + off + h * DHEAD + lane * 2;
  float v0 = bf2f(src[0]), v1 = bf2f(src[1]);
  float nn = v0*v0 + v1*v1;
  #pragma unroll
  for (int m = 1; m < 64; m <<= 1) nn += __shfl_xor(nn, m, 64);
  float Kh = headK[h];
  float sk = sqrtf(-Kh);
  float a = sk * sqrtf(nn);
  float f = (a < 1e-6f) ? (1.0f + a*a*(1.0f/6.0f)) : (sinhf(a) / a);
  u16* dst = Lout + (size_t)gid * DHEAD + lane * 2;
  dst[0] = f2bf(f * v0);
  dst[1] = f2bf(f * v1);
  if (lane == 0) l0[gid] = sqrtf(-1.0f/Kh + f*f*nn);
}

// ---- vtrans ----
__global__ void vtrans(const u16* __restrict__ vb, u16* __restrict__ VT,
                       int instride, int off) {
  __shared__ u16 tile[32][33];
  int bh = blockIdx.x;
  int b = bh >> 4, h = bh & 15;
  int s0 = blockIdx.y * 32, d0 = blockIdx.z * 32;
  int tx = threadIdx.x, ty = threadIdx.y;
  #pragma unroll
  for (int i = 0; i < 4; ++i)
    tile[ty + 8*i][tx] = vb[((size_t)(b*SEQ + s0 + ty + 8*i)) * instride + off + h*DHEAD + d0 + tx];
  __syncthreads();
  #pragma unroll
  for (int i = 0; i < 4; ++i)
    VT[((size_t)bh*DHEAD + d0 + ty + 8*i) * SEQ + s0 + tx] = tile[tx][ty + 8*i];
}

// -------- flash attention v4: LDS double-buffer via gload16, swizzled, raw barriers --------
// 1D grid, bh = id&31 (XCD-local heads), qb = 15-(id>>5). 4 waves x 32 q-rows = 128 q/block.
__global__ __launch_bounds__(256, 2) void attn_kernel(
    const u16* __restrict__ Ql, const u16* __restrict__ Kl,
    const u16* __restrict__ VT, const float* __restrict__ ql0,
    const float* __restrict__ kl0, const float* __restrict__ headK,
    u16* __restrict__ out) {
  __shared__ u16 klds[2][32 * 128];   // [krow][chunk-swizzled d], no pad (gload16 dest)
  __shared__ u16 vlds[2][128 * 32];   // [drow][chunk-swizzled kpos]
  __shared__ u16 plds[4][32 * 36];    // per-wave P buffer, stride 36 (conflict-free)
  const int tid = threadIdx.x, w = tid >> 6, lane = tid & 63;
  const int lrow = lane & 15, kq = lane >> 4;
  const int id = blockIdx.x;
  const int bh = id & 31;
  const int qb = 15 - (id >> 5);      // long blocks first
  const int q0 = qb * 128 + w * 32;
  const int b = bh >> 4, h = bh & 15;
  const float Kh = headK[h];
  const float LOG2E = 1.44269504088896f;
  const float isd = 0.088388347648318447f;   // 1/sqrt(128)
  const float sc_mul = 2.0f * isd * LOG2E;
  const float sc_add = (-2.0f / Kh) * isd * LOG2E;

  const u16* kbase  = Kl + (size_t)bh * SEQ * DHEAD;
  const u16* vtbase = VT + (size_t)bh * DHEAD * SEQ;
  const float* kl0b = kl0 + (size_t)bh * SEQ;
  u16* pw = &plds[w][0];

  // preload Q fragments (2 m-tiles x 4 d-chunks) and q0 components
  bf16x8 aq[2][4];
  const u16* qbase = Ql + ((size_t)bh * SEQ + q0) * DHEAD;
  #pragma unroll
  for (int m = 0; m < 2; ++m)
    #pragma unroll
    for (int dc = 0; dc < 4; ++dc)
      aq[m][dc] = *(const bf16x8*)&qbase[(size_t)(m*16 + lrow) * DHEAD + dc*32 + kq*8];
  float q0r[2][4];
  #pragma unroll
  for (int m = 0; m < 2; ++m)
    #pragma unroll
    for (int r = 0; r < 4; ++r)
      q0r[m][r] = ql0[(size_t)bh * SEQ + q0 + m*16 + kq*4 + r];

  // staging: wave w loads K rows [w*8, w*8+8) (2x gload16) and V^T rows [w*32, w*32+32)
  auto stage = [&](int k0, int buf) {
    #pragma unroll
    for (int i = 0; i < 2; ++i) {
      int rl = w*8 + i*4 + (lane >> 4);           // local k-row 0..31
      int c = (lane & 15) ^ (rl & 15);            // actual chunk for swizzled slot
      gload16(kbase + ((size_t)(k0 + rl)) * DHEAD + c * 8,
              &klds[buf][(w*8 + i*4) * 128]);
    }
    #pragma unroll
    for (int i = 0; i < 2; ++i) {
      int rl = w*32 + i*16 + (lane >> 2);         // d-row 0..127
      int c = (lane & 3) ^ ((rl >> 1) & 3);
      gload16(vtbase + (size_t)rl * SEQ + k0 + c * 8,
              &vlds[buf][(w*32 + i*16) * 32]);
    }
  };

  float lacc[2][4] = {};
  f32x4 o[2][8] = {};
  const int niter = qb * 4 + 4;

  stage(0, 0);
  for (int i = 0; i < niter; ++i) {
    const int k0 = i * 32, buf = i & 1;
    float kc0 = kl0b[k0 + lrow];
    float kc1 = kl0b[k0 + 16 + lrow];
    if (i + 1 < niter) {
      stage(k0 + 32, buf ^ 1);
      asm volatile("s_waitcnt vmcnt(4)" ::: "memory");
    } else {
      asm volatile("s_waitcnt vmcnt(0)" ::: "memory");
    }
    asm volatile("s_barrier" ::: "memory");

    // ---- QK^T ----
    f32x4 sc[2][2] = {};
    #pragma unroll
    for (int dc = 0; dc < 4; ++dc) {
      int c = dc*4 + kq;
      bf16x8 bk0 = *(const bf16x8*)&klds[buf][lrow*128        + (c ^ (lrow & 15)) * 8];
      bf16x8 bk1 = *(const bf16x8*)&klds[buf][(16 + lrow)*128 + (c ^ ((16 + lrow) & 15)) * 8];
      #pragma unroll
      for (int m = 0; m < 2; ++m) {
        sc[m][0] = __builtin_amdgcn_mfma_f32_16x16x32_bf16(aq[m][dc], bk0, sc[m][0], 0, 0, 0);
        sc[m][1] = __builtin_amdgcn_mfma_f32_16x16x32_bf16(aq[m][dc], bk1, sc[m][1], 0, 0, 0);
      }
    }
    // ---- softmax numerator (max fixed at 0: Lorentz scores <= 0), causal mask ----
    #pragma unroll
    for (int m = 0; m < 2; ++m)
      #pragma unroll
      for (int r = 0; r < 4; ++r) {
        int qg = q0 + m*16 + kq*4 + r;
        float p0 = exp2f((sc[m][0][r] - q0r[m][r] * kc0) * sc_mul + sc_add);
        float p1 = exp2f((sc[m][1][r] - q0r[m][r] * kc1) * sc_mul + sc_add);
        p0 = (k0 + lrow      <= qg) ? p0 : 0.f;
        p1 = (k0 + 16 + lrow <= qg) ? p1 : 0.f;
        lacc[m][r] += p0 + p1;
        pw[(m*16 + kq*4 + r) * 36 + lrow]      = f2bf(p0);
        pw[(m*16 + kq*4 + r) * 36 + 16 + lrow] = f2bf(p1);
      }
    // ---- P @ V ----
    bf16x8 ap0 = *(const bf16x8*)&pw[(size_t)lrow * 36 + kq*8];
    bf16x8 ap1 = *(const bf16x8*)&pw[(size_t)(16 + lrow) * 36 + kq*8];
    int vc = (kq ^ ((lrow >> 1) & 3)) * 8;
    #pragma unroll
    for (int n = 0; n < 8; ++n) {
      bf16x8 bv = *(const bf16x8*)&vlds[buf][(n*16 + lrow) * 32 + vc];
      o[0][n] = __builtin_amdgcn_mfma_f32_16x16x32_bf16(ap0, bv, o[0][n], 0, 0, 0);
      o[1][n] = __builtin_amdgcn_mfma_f32_16x16x32_bf16(ap1, bv, o[1][n], 0, 0, 0);
    }
    asm volatile("s_barrier" ::: "memory");
  }

  // ---- finalize ----
  float rcl[2][4];
  #pragma unroll
  for (int m = 0; m < 2; ++m)
    #pragma unroll
    for (int r = 0; r < 4; ++r) {
      float s = lacc[m][r];
      #pragma unroll
      for (int mm = 1; mm < 16; mm <<= 1) s += __shfl_xor(s, mm, 16);
      rcl[m][r] = 1.0f / s;
    }
  #pragma unroll
  for (int m = 0; m < 2; ++m)
    #pragma unroll
    for (int n = 0; n < 8; ++n)
      #pragma unroll
      for (int r = 0; r < 4; ++r) {
        int qg = q0 + m*16 + kq*4 + r;
        out[((size_t)b * SEQ + qg) * DMODEL + h * DHEAD + n*16 + lrow] =
            f2bf(o[m][n][r] * rcl[m][r]);
      }
}

extern "C" void kernel_launch(void* const* d_in, const int* in_sizes, int n_in,
                              void* d_out, int out_size, void* d_ws, size_t ws_size,
                              hipStream_t stream) {
  const float* x      = (const float*)d_in[0];
  const float* scale1 = (const float*)d_in[2];
  const float* scale2 = (const float*)d_in[3];
  const float* Wq     = (const float*)d_in[4];
  const float* Wk     = (const float*)d_in[5];
  const float* Wv     = (const float*)d_in[6];
  const float* Wo     = (const float*)d_in[7];
  const float* headK  = (const float*)d_in[8];
  const float* W1     = (const float*)d_in[9];
  const float* W2     = (const float*)d_in[10];
  float* out = (float*)d_out;

  char* p = (char*)d_ws;
  size_t off = 0;
  auto take = [&](size_t bytes) -> char* {
    char* r = p + off;
    off += (bytes + 255) & ~(size_t)255;
    return r;
  };
  u16* WqT = (u16*)take((size_t)DMODEL*DMODEL*2);   // WqT/WkT/WvT contiguous => (6144,2048)
  u16* WkT = (u16*)take((size_t)DMODEL*DMODEL*2);
  u16* WvT = (u16*)take((size_t)DMODEL*DMODEL*2);
  u16* WoT = (u16*)take((size_t)DMODEL*DMODEL*2);
  u16* W1T = (u16*)take((size_t)DMODEL*DFFN*2);
  u16* W2T = (u16*)take((size_t)DMODEL*DFFN*2);
  float* vres = (float*)take((size_t)MROWS*DMODEL*4);   // v1 -> u2 -> u3 (in place)
  u16* tbuf = (u16*)take((size_t)MROWS*DMODEL*2);       // t1, attn_out, t2
  u16* qkvb = (u16*)take((size_t)MROWS*3*DMODEL*2);     // fused QKV out (4096 x 6144)
  u16* Qlb  = (u16*)take((size_t)MROWS*DMODEL*2);       // qkvb+Qlb = 64MB => FFN hidden
  u16* Klb  = (u16*)take((size_t)MROWS*DMODEL*2);
  u16* VTb  = (u16*)take((size_t)MROWS*DMODEL*2);
  float* q0b = (float*)take((size_t)NB*NHEAD*SEQ*4);
  float* k0b = (float*)take((size_t)NB*NHEAD*SEQ*4);
  u16* hbuf = qkvb;     // reuse qkvb..Qlb contiguous 64MB = MROWS*DFFN bf16
  u16* attnout = tbuf;  // t1 consumed by QKV gemm before attention writes here

  dim3 tb(32, 8);
  transpose_w<<<dim3(DMODEL/32, DMODEL/32), tb, 0, stream>>>(Wq, WqT, DMODEL, DMODEL);
  transpose_w<<<dim3(DMODEL/32, DMODEL/32), tb, 0, stream>>>(Wk, WkT, DMODEL, DMODEL);
  transpose_w<<<dim3(DMODEL/32, DMODEL/32), tb, 0, stream>>>(Wv, WvT, DMODEL, DMODEL);
  transpose_w<<<dim3(DMODEL/32, DMODEL/32), tb, 0, stream>>>(Wo, WoT, DMODEL, DMODEL);
  transpose_w<<<dim3(DFFN/32,   DMODEL/32), tb, 0, stream>>>(W1, W1T, DMODEL, DFFN);
  transpose_w<<<dim3(DMODEL/32, DFFN/32),   tb, 0, stream>>>(W2, W2T, DFFN, DMODEL);

  ln_first<<<MROWS, 256, 0, stream>>>(x, scale1, vres, tbuf);

  // fused QKV: N = 6144
  gemm_bt<0><<<dim3(3*DMODEL/128, MROWS/128), 256, 0, stream>>>(tbuf, WqT, qkvb, nullptr, nullptr, MROWS, 3*DMODEL, DMODEL);

  prep_qk<<<NB*NHEAD*SEQ/4, 256, 0, stream>>>(qkvb, headK, Qlb, q0b, 3*DMODEL, 0);
  prep_qk<<<NB*NHEAD*SEQ/4, 256, 0, stream>>>(qkvb, headK, Klb, k0b, 3*DMODEL, DMODEL);
  vtrans<<<dim3(NB*NHEAD, SEQ/32, DHEAD/32), tb, 0, stream>>>(qkvb, VTb, 3*DMODEL, 2*DMODEL);

  attn_kernel<<<dim3(512), 256, 0, stream>>>(Qlb, Klb, VTb, q0b, k0b, headK, attnout);

  gemm_bt<1><<<dim3(DMODEL/128, MROWS/128), 256, 0, stream>>>(attnout, WoT, nullptr, vres, vres, MROWS, DMODEL, DMODEL);

  rms_mid<<<MROWS, 256, 0, stream>>>(vres, scale2, tbuf);

  gemm_bt<2><<<dim3(DFFN/128, MROWS/128), 256, 0, stream>>>(tbuf, W1T, hbuf, nullptr, nullptr, MROWS, DFFN, DMODEL);

  gemm_bt<1><<<dim3(DMODEL/128, MROWS/128), 256, 0, stream>>>(hbuf, W2T, nullptr, vres, vres, MROWS, DMODEL, DFFN);

  final_exp<<<MROWS, 256, 0, stream>>>(vres, out);

  (void)in_sizes; (void)n_in; (void)out_size; (void)ws_size;
}